// Round 6
// baseline (27378.885 us; speedup 1.0000x reference)
//
#include <hip/hip_runtime.h>
#include <hip/hip_bf16.h>

// Persistent-weights LSTM for MI355X.  B=32, T=1024, D_IN=512, H=512.
// R6 = R4 skeleton (64 WGs x 256 thr, 8 h-cols/WG, 128-VGPR weight slice,
// self-validating 8B h-records {epoch|2xf16}) with the staging tail removed:
//   - one-shot convert kernel writes x as f16 in A-fragment order to d_ws;
//     per-step x-path = 16 direct global 16B loads/lane (L2-hot, prefetched
//     a full step ahead). No cvt, no ds_write, no xbuf (LDS 75->9 KB).
//   - x-half MFMAs run BEFORE the poll (xf registers die before d[64] is
//     live: peak ~260 VGPR, avoids R5's 256-cap spill).
//   - slow-path poll spins on 4B epoch hi-words only, then one 4B lo pass
//     (safe: records stored as single 8B atomics; lo-read after observing
//     the epoch returns matching data).
// Publish is still ONE fire-and-forget 8B agent-scope store per thread-pair:
// no drain, no flags, no release fence. 1 __syncthreads per step.

#define T_STEPS 1024
#define BATCH   32
#define DIN     512
#define H       512
#define NWG     64
#define HC      8
#define GSTRIDE 34             // padded f32 row stride of LDS gate tile
#define RECS_PER_PARITY 8192   // 16 kk * 512

typedef _Float16 half8  __attribute__((ext_vector_type(8)));
typedef float    f32x4  __attribute__((ext_vector_type(4)));
typedef unsigned long long u64;
typedef unsigned int       u32;

#define AT_LD_U64(p)   __hip_atomic_load((const u64*)(p), __ATOMIC_RELAXED, __HIP_MEMORY_SCOPE_AGENT)
#define AT_LD_U32(p)   __hip_atomic_load((const u32*)(p), __ATOMIC_RELAXED, __HIP_MEMORY_SCOPE_AGENT)
#define AT_ST_U64(p,v) __hip_atomic_store((u64*)(p), (v), __ATOMIC_RELAXED, __HIP_MEMORY_SCOPE_AGENT)

__device__ __forceinline__ float sigmoidf_(float x) {
    return 1.0f / (1.0f + __expf(-x));
}
__device__ __forceinline__ float tanhf_(float x) {
    return 1.0f - 2.0f / (1.0f + __expf(2.0f * x));
}

// ---- one-shot: x [B][T][DIN] f32  ->  x16 in A-fragment order ------------
// x16 16B-chunk index: (t*16 + kk)*128 + row*4 + kq   holds
//   x[row][t][kk*32 + kq*8 + j], j=0..7  as f16.
__global__ __launch_bounds__(256) void convert_x(
    const float* __restrict__ x, _Float16* __restrict__ x16)
{
    const int gid = blockIdx.x * 256 + threadIdx.x;   // 32*1024*64 = 2M
    const int c8  = gid & 63;                         // column octet
    const int t   = (gid >> 6) & 1023;
    const int row = gid >> 16;                        // batch
    const float* src = x + ((size_t)row * T_STEPS + t) * DIN + c8 * 8;
    float4 v0 = *(const float4*)(src);
    float4 v1 = *(const float4*)(src + 4);
    half8 h = { (_Float16)v0.x, (_Float16)v0.y, (_Float16)v0.z, (_Float16)v0.w,
                (_Float16)v1.x, (_Float16)v1.y, (_Float16)v1.z, (_Float16)v1.w };
    const int kk = c8 >> 2, kq = c8 & 3;
    *(half8*)(x16 + ((size_t)(t * 16 + kk) * 128 + row * 4 + kq) * 8) = h;
}

__global__ __launch_bounds__(256, 1) void lstm_persistent(
    const float* __restrict__ init_states,
    const float* __restrict__ Wi, const float* __restrict__ Ui, const float* __restrict__ bi,
    const float* __restrict__ Wf, const float* __restrict__ Uf, const float* __restrict__ bf,
    const float* __restrict__ Wc, const float* __restrict__ Uc, const float* __restrict__ bc,
    const float* __restrict__ Wo, const float* __restrict__ Uo, const float* __restrict__ bo,
    float* __restrict__ out,
    u64* __restrict__ hrec,          // 2 parities x 8192 x 8B
    const _Float16* __restrict__ x16)
{
    __shared__ float gbuf[2 * BATCH * GSTRIDE];   // ~8.7 KB (only LDS)

    const int tid  = threadIdx.x;
    const int wg   = blockIdx.x;
    const int lane = tid & 63;
    const int wave = tid >> 6;
    const int mt   = wave & 1;
    const int nt   = wave >> 1;
    const int row  = mt * 16 + (lane & 15);
    const int kq   = lane >> 4;
    const int rq   = row * 4 + kq;        // 16B-chunk index within (t,kk)

    // ---- elementwise identity ---------------------------------------------
    const int eb   = tid >> 3;            // batch 0..31
    const int ej   = tid & 7;             // local h-col 0..7
    const int ecol = wg * HC + ej;
    const int widx = (wg >> 2) * 512 + (ej >> 1) * 128 + eb * 4 + (wg & 3);

    // ---- publish h0 FIRST (epoch 1, parity 0) -----------------------------
    float c_state = init_states[BATCH * H + eb * H + ecol];
    {
        _Float16 h0 = (_Float16)init_states[eb * H + ecol];
        u32 hu  = (u32)__builtin_bit_cast(unsigned short, h0);
        u32 oth = __shfl_down(hu, 1);
        if ((tid & 1) == 0)
            AT_ST_U64(&hrec[widx], ((u64)1u << 32) | (u64)(hu | (oth << 16)));
    }

    // ---- one-time: weight B-fragments into VGPRs --------------------------
    const int n_local = lane & 15;
    const int gi   = nt * 2 + (n_local >> 3);
    const int wcol = wg * HC + (n_local & 7);
    const float* Wmat = (gi == 0) ? Wi : (gi == 1) ? Wf : (gi == 2) ? Wc : Wo;
    const float* Umat = (gi == 0) ? Ui : (gi == 1) ? Uf : (gi == 2) ? Uc : Uo;

    half8 bfrag[32];                      // 128 VGPRs/lane, persistent
    #pragma unroll
    for (int kk = 0; kk < 16; ++kk) {
        #pragma unroll
        for (int jj = 0; jj < 8; ++jj) {
            int k = kk * 32 + kq * 8 + jj;
            bfrag[kk][jj]      = (_Float16)Wmat[k * H + wcol];
            bfrag[16 + kk][jj] = (_Float16)Umat[k * H + wcol];
        }
    }

    const float bi_v = bi[ecol], bf_v = bf[ecol], bc_v = bc[ecol], bo_v = bo[ecol];

    // ---- x-fragment prefetch: 16 direct 16B global loads ------------------
    half8 xf[16];
    auto xload = [&](int t) {
        const _Float16* p = x16 + ((size_t)t * 2048 + rq) * 8;
        #pragma unroll
        for (int kk = 0; kk < 16; ++kk)
            xf[kk] = *(const half8*)(p + (size_t)kk * 1024);
    };
    xload(0);

    const int ridx_base = rq;

    // ---- main recurrence --------------------------------------------------
    for (int t = 0; t < T_STEPS; ++t) {
        // x-half MFMAs first (xf prefetched a full step ago; frees xf regs)
        f32x4 ax0 = {0.f, 0.f, 0.f, 0.f};
        f32x4 ax1 = {0.f, 0.f, 0.f, 0.f};
        #pragma unroll
        for (int kk = 0; kk < 16; kk += 2) {
            ax0 = __builtin_amdgcn_mfma_f32_16x16x32_f16(xf[kk],     bfrag[kk],     ax0, 0, 0, 0);
            ax1 = __builtin_amdgcn_mfma_f32_16x16x32_f16(xf[kk + 1], bfrag[kk + 1], ax1, 0, 0, 0);
        }

        // poll-load the 64 self-validating records (fast: full 8B pass)
        const u64* rb = hrec + (size_t)(t & 1) * RECS_PER_PARITY;
        const u32 target = (u32)(t + 1);
        u32 d[64];
        {
            u32 ok = 1u;
            #pragma unroll
            for (int g = 0; g < 4; ++g) {
                u64 r[16];
                #pragma unroll
                for (int kk = 0; kk < 4; ++kk)
                    #pragma unroll
                    for (int s = 0; s < 4; ++s)
                        r[kk * 4 + s] = AT_LD_U64(&rb[(g * 4 + kk) * 512 + s * 128 + ridx_base]);
                #pragma unroll
                for (int i = 0; i < 16; ++i) {
                    d[g * 16 + i] = (u32)r[i];
                    ok &= ((u32)(r[i] >> 32) == target) ? 1u : 0u;
                }
            }
            if (!__all((int)ok)) {
                // slow path: spin on 4B epoch hi-words, then one 4B lo pass
                unsigned spins = 0;
                for (;;) {
                    u32 ok2 = 1u;
                    #pragma unroll
                    for (int kk = 0; kk < 16; ++kk)
                        #pragma unroll
                        for (int s = 0; s < 4; ++s) {
                            u32 e = AT_LD_U32(((const u32*)&rb[kk * 512 + s * 128 + ridx_base]) + 1);
                            ok2 &= (e == target) ? 1u : 0u;
                        }
                    if (__all((int)ok2)) break;
                    if (++spins > 300000u) break;   // safety valve
                }
                #pragma unroll
                for (int kk = 0; kk < 16; ++kk)
                    #pragma unroll
                    for (int s = 0; s < 4; ++s)
                        d[kk * 4 + s] = AT_LD_U32((const u32*)&rb[kk * 512 + s * 128 + ridx_base]);
            }
        }
        __builtin_amdgcn_fence(__ATOMIC_ACQUIRE, "workgroup");

        // h-half matmul
        float* gb = &gbuf[(t & 1) * (BATCH * GSTRIDE)];
        {
            f32x4 ah0 = ax0, ah1 = ax1;
            #pragma unroll
            for (int kk = 0; kk < 16; kk += 2) {
                union { u32 w[4]; half8 h; } A0, A1;
                #pragma unroll
                for (int s = 0; s < 4; ++s) {
                    A0.w[s] = d[kk * 4 + s];
                    A1.w[s] = d[(kk + 1) * 4 + s];
                }
                ah0 = __builtin_amdgcn_mfma_f32_16x16x32_f16(A0.h, bfrag[16 + kk],     ah0, 0, 0, 0);
                ah1 = __builtin_amdgcn_mfma_f32_16x16x32_f16(A1.h, bfrag[16 + kk + 1], ah1, 0, 0, 0);
            }
            #pragma unroll
            for (int r = 0; r < 4; ++r) {
                // C/D layout: col = lane&15, row = (lane>>4)*4 + r
                gb[(mt * 16 + kq * 4 + r) * GSTRIDE + nt * 16 + n_local] =
                    ah0[r] + ah1[r];
            }
        }
        __syncthreads();   // the ONLY barrier per step

        // elementwise gates + state update + immediate h publish
        float h_val;
        {
            float pi = gb[eb * GSTRIDE + ej]      + bi_v;
            float pf = gb[eb * GSTRIDE + 8 + ej]  + bf_v;
            float pg = gb[eb * GSTRIDE + 16 + ej] + bc_v;
            float po = gb[eb * GSTRIDE + 24 + ej] + bo_v;
            float ig = sigmoidf_(pi);
            float fg = sigmoidf_(pf);
            float gg = tanhf_(pg);
            float og = sigmoidf_(po);
            c_state  = fg * c_state + ig * gg;
            h_val    = og * tanhf_(c_state);

            if (t + 1 < T_STEPS) {
                _Float16 hh = (_Float16)h_val;
                u32 hu  = (u32)__builtin_bit_cast(unsigned short, hh);
                u32 oth = __shfl_down(hu, 1);
                if ((tid & 1) == 0)
                    AT_ST_U64(&hrec[(size_t)((t + 1) & 1) * RECS_PER_PARITY + widx],
                              ((u64)(u32)(t + 2) << 32) | (u64)(hu | (oth << 16)));
            }
        }

        // ---- off-critical-path tail: out store + next x prefetch ----------
        out[((size_t)eb * T_STEPS + t) * H + ecol] = h_val;
        if (t + 1 < T_STEPS) xload(t + 1);
    }
}

extern "C" void kernel_launch(void* const* d_in, const int* in_sizes, int n_in,
                              void* d_out, int out_size, void* d_ws, size_t ws_size,
                              hipStream_t stream) {
    const float* x           = (const float*)d_in[0];
    const float* init_states = (const float*)d_in[1];
    const float* Wi = (const float*)d_in[2];
    const float* Ui = (const float*)d_in[3];
    const float* bi = (const float*)d_in[4];
    const float* Wf = (const float*)d_in[5];
    const float* Uf = (const float*)d_in[6];
    const float* bf = (const float*)d_in[7];
    const float* Wc = (const float*)d_in[8];
    const float* Uc = (const float*)d_in[9];
    const float* bc = (const float*)d_in[10];
    const float* Wo = (const float*)d_in[11];
    const float* Uo = (const float*)d_in[12];
    const float* bo = (const float*)d_in[13];
    float* out = (float*)d_out;

    // ws layout: [0, 128 KB) h-record parities (epoch-validated; 0xAA poison
    // never matches a real epoch); [128 KB, 128 KB + 32 MB) f16 x in
    // A-fragment order, rewritten by convert_x every launch.
    unsigned char* ws = (unsigned char*)d_ws;
    u64*      hrec = (u64*)ws;
    _Float16* x16  = (_Float16*)(ws + 128 * 1024);

    // one-shot transpose/convert (stream-ordered before the persistent kernel;
    // kernel boundary写backs L2, so x16 is globally visible)
    convert_x<<<dim3((BATCH * T_STEPS * 64) / 256), dim3(256), 0, stream>>>(x, x16);

    lstm_persistent<<<dim3(NWG), dim3(256), 0, stream>>>(
        init_states, Wi, Ui, bi, Wf, Uf, bf, Wc, Uc, bc, Wo, Uo, bo,
        out, hrec, x16);
}